// Round 13
// baseline (452.522 us; speedup 1.0000x reference)
//
#include <hip/hip_runtime.h>

// MLA v3 forward, MI355X/gfx950. Round 13.
// - Attn: 32x32x16 MFMA, SINGLE-buffered global_load_lds staging (no reg
//   staging -> ~40 fewer VGPRs; combined VGPR+AGPR ~220 <= 256), linear LDS
//   with both-sides granule XOR (round-11-verified reads), launch_bounds
//   (256,2) to guarantee 2 waves/SIMD. LDS 59.4KB -> 2 blocks/CU.
// - Prep (f2b + 8 weight transposes + rope table) fused into ONE launch.
// - GEMMs identical to rounds 9-12.

typedef unsigned short u16;
typedef __attribute__((ext_vector_type(8))) short s16x8;
typedef __attribute__((ext_vector_type(4))) float f32x4;
typedef __attribute__((ext_vector_type(16))) float f32x16;
typedef __attribute__((ext_vector_type(8))) __bf16 bf16x8;
typedef __attribute__((ext_vector_type(4))) u16 u16x4;

#define S_LEN 2048
#define NH 16
#define HD 128
#define DQK 192
#define EMB 2048

#define GLOAD_LDS16(g, l)                                                      \
  __builtin_amdgcn_global_load_lds(                                            \
      (const __attribute__((address_space(1))) unsigned int*)(g),              \
      (__attribute__((address_space(3))) unsigned int*)(l), 16, 0, 0)

__device__ __forceinline__ u16 f2b(float f) {
  unsigned u = __builtin_bit_cast(unsigned, f);
  u += 0x7FFFu + ((u >> 16) & 1u);           // RNE to bf16
  return (u16)(u >> 16);
}
__device__ __forceinline__ float b2f(u16 v) {
  unsigned u = ((unsigned)v) << 16;
  return __builtin_bit_cast(float, u);
}
__device__ __forceinline__ bf16x8 ld_bf8(const u16* p) {
  return __builtin_bit_cast(bf16x8, *(const s16x8*)p);
}

// Transpose one 64x64 tile: in f32 [K][N] -> out bf16 [N][K].
__device__ __forceinline__ void transpose_tile(const float* __restrict__ in,
                                               u16* __restrict__ out,
                                               int K, int N, int local, int t,
                                               u16* T /* [64*72] LDS */) {
  int nt = N >> 6;
  int n0 = (local % nt) * 64, k0 = (local / nt) * 64;
#pragma unroll
  for (int r = 0; r < 4; ++r) {
    int kl = (t >> 4) + r * 16, nl = (t & 15) * 4;
    f32x4 v = *(const f32x4*)(in + (size_t)(k0 + kl) * N + n0 + nl);
#pragma unroll
    for (int j = 0; j < 4; ++j) T[(nl + j) * 72 + kl] = f2b(v[j]);
  }
  __syncthreads();
#pragma unroll
  for (int r = 0; r < 2; ++r) {
    int chunk = t + r * 256, nr = chunk >> 3, kc = (chunk & 7) * 8;
    *(s16x8*)(out + (size_t)(n0 + nr) * K + k0 + kc) = *(const s16x8*)(&T[nr * 72 + kc]);
  }
}

// Fused prep: [0,8192) f2b(x); then 8 weight transposes; then rope table.
__global__ __launch_bounds__(256) void prep_kernel(
    const float* __restrict__ xf, u16* __restrict__ XB,
    const float* __restrict__ wckvf, u16* __restrict__ WCKV_T,
    const float* __restrict__ wcqf,  u16* __restrict__ WCQ_T,
    const float* __restrict__ wkrf,  u16* __restrict__ WKR_T,
    const float* __restrict__ wkf,   u16* __restrict__ WK_T,
    const float* __restrict__ wvf,   u16* __restrict__ WV_T,
    const float* __restrict__ wqf,   u16* __restrict__ WQ_T,
    const float* __restrict__ wqrf,  u16* __restrict__ WQR_T,
    const float* __restrict__ wof,   u16* __restrict__ WO_T,
    float* __restrict__ cosT, float* __restrict__ sinT) {
  __shared__ u16 T[64 * 72];
  const int id = blockIdx.x, t = threadIdx.x;
  if (id < 8192) {                       // x f32 -> bf16, 4 el/thread
    int i = id * 256 + t;                // n4 = 2097152 exactly
    f32x4 v = *(const f32x4*)(xf + (size_t)i * 4);
    u16x4 o = { f2b(v[0]), f2b(v[1]), f2b(v[2]), f2b(v[3]) };
    *(u16x4*)(XB + (size_t)i * 4) = o;
  } else if (id < 8448)  { transpose_tile(wckvf, WCKV_T, 2048, 512,  id - 8192, t, T); }
  else if (id < 8704)    { transpose_tile(wcqf,  WCQ_T,  2048, 512,  id - 8448, t, T); }
  else if (id < 8736)    { transpose_tile(wkrf,  WKR_T,  2048, 64,   id - 8704, t, T); }
  else if (id < 8992)    { transpose_tile(wkf,   WK_T,   512,  2048, id - 8736, t, T); }
  else if (id < 9248)    { transpose_tile(wvf,   WV_T,   512,  2048, id - 8992, t, T); }
  else if (id < 9504)    { transpose_tile(wqf,   WQ_T,   512,  2048, id - 9248, t, T); }
  else if (id < 9632)    { transpose_tile(wqrf,  WQR_T,  512,  1024, id - 9504, t, T); }
  else if (id < 10656)   { transpose_tile(wof,   WO_T,   2048, 2048, id - 9632, t, T); }
  else {                                 // rope cos/sin table, 65536 entries
    int i2 = (id - 10656) * 256 + t;
    int s = i2 >> 5, i = i2 & 31;
    float inv = exp2f(-(float)i * (13.287712379549449f / 32.0f));
    float ang = (float)s * inv;
    cosT[i2] = cosf(ang);
    sinT[i2] = sinf(ang);
  }
}

// C = A[M,K](lda) @ BT[N,K]^T, bf16 in, fp32 accum. 128x128 tile, BK=64.
// LDS double-buffer, 1 barrier/iter; global_load_lds 16B, source-swizzled.
// MODE 0: bf16 [M,N]->Cout; MODE 1: fp32 [M,N]->Cout;
// MODE 4: col<2048 -> KCAT [b,h,s,192]; col>=2048 -> VT [b,h,d,s];
// MODE 5: col<2048 -> QCAT [b,h,s,192] scaled; col>=2048 -> QR [M,1024].
template<int MODE>
__global__ __launch_bounds__(256) void gemm_bt_kernel(const u16* __restrict__ A,
                                                      int lda,
                                                      const u16* __restrict__ BT,
                                                      void* __restrict__ Cout,
                                                      void* __restrict__ Cout2,
                                                      int M, int N, int K,
                                                      float scale) {
  __shared__ __align__(16) u16 As[2][128 * 64];
  __shared__ __align__(16) u16 Bs[2][128 * 64];
  const int t = threadIdx.x;
  const int lane = t & 63, wid = t >> 6;
  const int wr = (wid >> 1) * 64, wc = (wid & 1) * 64;
  const int bm0 = blockIdx.y * 128, bn0 = blockIdx.x * 128;
  const int lr = lane & 15, lg = lane >> 4;

  auto stage = [&](int k0, int buf) {
#pragma unroll
    for (int r = 0; r < 4; ++r) {
      int chunk = t + r * 256;
      int row = chunk >> 3, kcs = (chunk & 7) * 8;
      int kcg = kcs ^ ((row & 7) << 3);      // inverse swizzle on SOURCE
      GLOAD_LDS16(A + (size_t)(bm0 + row) * lda + k0 + kcg, &As[buf][chunk * 8]);
      GLOAD_LDS16(BT + (size_t)(bn0 + row) * K + k0 + kcg, &Bs[buf][chunk * 8]);
    }
  };

  f32x4 acc[4][4] = {};
  const int nt = K >> 6;
  stage(0, 0);
  for (int tk = 0; tk < nt; ++tk) {
    const int cur = tk & 1;
    __syncthreads();
    if (tk + 1 < nt) stage((tk + 1) << 6, cur ^ 1);
#pragma unroll
    for (int kk = 0; kk < 2; ++kk) {
      bf16x8 af[4], bfr[4];
      const int kbase = kk * 32 + lg * 8;
#pragma unroll
      for (int m = 0; m < 4; ++m) {
        int row = wr + m * 16 + lr;
        af[m] = ld_bf8(&As[cur][row * 64 + (kbase ^ ((row & 7) << 3))]);
      }
#pragma unroll
      for (int n = 0; n < 4; ++n) {
        int row = wc + n * 16 + lr;
        bfr[n] = ld_bf8(&Bs[cur][row * 64 + (kbase ^ ((row & 7) << 3))]);
      }
#pragma unroll
      for (int m = 0; m < 4; ++m)
#pragma unroll
        for (int n = 0; n < 4; ++n)
          acc[m][n] = __builtin_amdgcn_mfma_f32_16x16x32_bf16(af[m], bfr[n], acc[m][n], 0, 0, 0);
    }
  }

  // C/D layout: col = lane&15, row = (lane>>4)*4 + reg
#pragma unroll
  for (int m = 0; m < 4; ++m)
#pragma unroll
    for (int n = 0; n < 4; ++n)
#pragma unroll
      for (int rg = 0; rg < 4; ++rg) {
        int row = bm0 + wr + m * 16 + lg * 4 + rg;
        int col = bn0 + wc + n * 16 + lr;
        if (col >= N) continue;
        float v = acc[m][n][rg];
        if (MODE == 0) {
          ((u16*)Cout)[(size_t)row * N + col] = f2b(v * scale);
        } else if (MODE == 1) {
          ((float*)Cout)[(size_t)row * N + col] = v * scale;
        } else if (MODE == 4) {
          int bb = row >> 11, s = row & 2047;
          if (col < 2048) {
            int h = col >> 7, d = col & 127;
            ((u16*)Cout)[((size_t)(bb * NH + h) * S_LEN + s) * DQK + d] = f2b(v);
          } else {
            int c2 = col - 2048, h = c2 >> 7, d = c2 & 127;
            ((u16*)Cout2)[((size_t)(bb * NH + h) * HD + d) * S_LEN + s] = f2b(v);
          }
        } else {  // MODE 5
          int bb = row >> 11, s = row & 2047;
          if (col < 2048) {
            int h = col >> 7, d = col & 127;
            ((u16*)Cout)[((size_t)(bb * NH + h) * S_LEN + s) * DQK + d] = f2b(v * scale);
          } else {
            ((u16*)Cout2)[(size_t)row * 1024 + (col - 2048)] = f2b(v);
          }
        }
      }
}

// Fill rope halves of Qcat/Kcat. kr lives in CC cols 1024..1087 (stride 1088).
__global__ __launch_bounds__(256) void rope_assemble_kernel(const u16* __restrict__ qr,
                                                            const u16* __restrict__ cc,
                                                            const float* __restrict__ cosT,
                                                            const float* __restrict__ sinT,
                                                            u16* __restrict__ Qcat,
                                                            u16* __restrict__ Kcat) {
  int id = blockIdx.x * 256 + threadIdx.x;   // B*H*S*32 = 2^21
  int i = id & 31;
  int s = (id >> 5) & 2047;
  int h = (id >> 16) & 15;
  int b = id >> 20;
  float c = cosT[(s << 5) + i], sn = sinT[(s << 5) + i];
  const float SC = 0.07216878364870323f;     // 1/sqrt(192)

  size_t qbase = ((size_t)b * S_LEN + s) * 1024 + h * 64 + 2 * i;
  float qe = b2f(qr[qbase]), qo = b2f(qr[qbase + 1]);
  size_t obase = ((size_t)(b * NH + h) * S_LEN + s) * DQK + HD + 2 * i;
  Qcat[obase]     = f2b((qe * c - qo * sn) * SC);
  Qcat[obase + 1] = f2b((qe * sn + qo * c) * SC);

  size_t kbase = ((size_t)b * S_LEN + s) * 1088 + 1024 + 2 * i;
  float ke = b2f(cc[kbase]), ko = b2f(cc[kbase + 1]);
  Kcat[obase]     = f2b(ke * c - ko * sn);
  Kcat[obase + 1] = f2b(ke * sn + ko * c);
}

// Flash attention, causal, 32x32x16 MFMA. 4 waves x 32 q-rows (QBLK=128),
// kv tile 64. Grid 512 balanced (qb = p8<8 ? p8 : 23-p8).
// Single-buffered global_load_lds staging (no staging regs), linear LDS,
// both-sides granule XOR: dest granule = src granule ^ (row&7).
// launch_bounds(256,2): combined regs <= 256 -> 2 waves/SIMD guaranteed.
// Fragment layouts (32x32x16, m74/m101): A row=lane&31, k=(lane>>5)*8+e;
// B col=lane&31, k=(lane>>5)*8+e; C col=lane&31, row=(r&3)+8*(r>>2)+4*(lane>>5).
__global__ __launch_bounds__(256, 2) void attn_kernel(const u16* __restrict__ Q,
                                                      const u16* __restrict__ K,
                                                      const u16* __restrict__ VT,
                                                      u16* __restrict__ O) {
  __shared__ __align__(16) u16 Ks[64 * 192];   // linear [kv][d granules swz]
  __shared__ __align__(16) u16 Vs[128 * 64];   // linear [d][kv granules swz]
  __shared__ u16 Ps[4 * 32 * 72];              // per-wave [q][kv], stride 72
  const int id = blockIdx.x;
  const int p8 = id >> 5, hb = id & 31;
  const int h = hb & 15, b = hb >> 4;
  const int qb = (p8 < 8) ? p8 : 23 - p8;
  const int q0 = qb * 128;
  const int t = threadIdx.x, lane = t & 63, wid = t >> 6;
  const int lc = lane & 31, hi = lane >> 5;
  const size_t qk_head = (size_t)(b * NH + h) * S_LEN * DQK;
  const size_t vt_head = (size_t)(b * NH + h) * HD * S_LEN;

  auto stage = [&](int kt) {
#pragma unroll
    for (int r = 0; r < 6; ++r) {        // K tile 64x192: 1536 16B chunks
      int c = t + r * 256, row = c / 24, g = c % 24;
      int sg = g ^ (row & 7);            // inverse swizzle on SOURCE
      GLOAD_LDS16(K + qk_head + (size_t)(kt * 64 + row) * DQK + sg * 8,
                  &Ks[c * 8]);
    }
#pragma unroll
    for (int r = 0; r < 4; ++r) {        // V tile 128x64: 1024 16B chunks
      int c = t + r * 256, d = c >> 3, g = c & 7;
      int sg = g ^ (d & 7);
      GLOAD_LDS16(VT + vt_head + (size_t)d * S_LEN + kt * 64 + sg * 8,
                  &Vs[c * 8]);
    }
  };

  // Q fragments: wave's 32 rows x 192, 12 k-steps of 16
  bf16x8 qa[12];
  {
    const u16* qrow = Q + qk_head + (size_t)(q0 + wid * 32 + lc) * DQK;
#pragma unroll
    for (int ks = 0; ks < 12; ++ks) qa[ks] = ld_bf8(qrow + ks * 16 + hi * 8);
  }

  f32x16 acc_o[4] = {};
  float m_r[16], l_r[16];
#pragma unroll
  for (int r = 0; r < 16; ++r) { m_r[r] = -INFINITY; l_r[r] = 0.f; }

  u16* psw = &Ps[wid * (32 * 72)];
  const int nt = 2 * qb + 2;
#pragma unroll 1
  for (int kt = 0; kt < nt; ++kt) {
    __syncthreads();                     // previous compute done reading LDS
    stage(kt);                           // async global->LDS
    __syncthreads();                     // vmcnt drained -> tile visible

    // S = Q K^T : two 32x32 kv-blocks
    f32x16 sc[2];
#pragma unroll
    for (int cb = 0; cb < 2; ++cb) {
      f32x16 sv = {};
#pragma unroll
      for (int ks = 0; ks < 12; ++ks) {
        bf16x8 kb = ld_bf8(&Ks[(cb * 32 + lc) * 192 +
                               ((ks * 2 + hi) ^ (lc & 7)) * 8]);
        sv = __builtin_amdgcn_mfma_f32_32x32x16_bf16(qa[ks], kb, sv, 0, 0, 0);
      }
      sc[cb] = sv;
    }

    if (kt >= 2 * qb) {              // diagonal tiles: causal mask
#pragma unroll
      for (int cb = 0; cb < 2; ++cb)
#pragma unroll
        for (int r = 0; r < 16; ++r) {
          int q_g = q0 + wid * 32 + (r & 3) + 8 * (r >> 2) + 4 * hi;
          int kv_g = kt * 64 + cb * 32 + lc;
          if (kv_g > q_g) sc[cb][r] = -INFINITY;
        }
    }

    float pmax[16];
#pragma unroll
    for (int r = 0; r < 16; ++r) pmax[r] = fmaxf(sc[0][r], sc[1][r]);
#pragma unroll
    for (int off = 1; off < 32; off <<= 1)
#pragma unroll
      for (int r = 0; r < 16; ++r)
        pmax[r] = fmaxf(pmax[r], __shfl_xor(pmax[r], off, 64));

#pragma unroll
    for (int r = 0; r < 16; ++r) {
      float mn = fmaxf(m_r[r], pmax[r]);
      float alpha = __expf(m_r[r] - mn);
      m_r[r] = mn;
      l_r[r] *= alpha;
#pragma unroll
      for (int db = 0; db < 4; ++db) acc_o[db][r] *= alpha;
    }

    float ps[16];
#pragma unroll
    for (int r = 0; r < 16; ++r) ps[r] = 0.f;
#pragma unroll
    for (int cb = 0; cb < 2; ++cb)
#pragma unroll
      for (int r = 0; r < 16; ++r) {
        float pv = __expf(sc[cb][r] - m_r[r]);
        ps[r] += pv;
        int qrow = (r & 3) + 8 * (r >> 2) + 4 * hi;
        psw[qrow * 72 + cb * 32 + lc] = f2b(pv);
      }
#pragma unroll
    for (int off = 1; off < 32; off <<= 1)
#pragma unroll
      for (int r = 0; r < 16; ++r)
        ps[r] += __shfl_xor(ps[r], off, 64);
#pragma unroll
    for (int r = 0; r < 16; ++r) l_r[r] += ps[r];

    // PV: P (A-frag, row=q=lc, k=kv) x V (B-frag, col=d, k=kv)
    bf16x8 pa[4];
#pragma unroll
    for (int ks = 0; ks < 4; ++ks)
      pa[ks] = ld_bf8(&psw[lc * 72 + ks * 16 + hi * 8]);
#pragma unroll
    for (int db = 0; db < 4; ++db) {
#pragma unroll
      for (int ks = 0; ks < 4; ++ks) {
        bf16x8 vb = ld_bf8(&Vs[(db * 32 + lc) * 64 +
                               ((ks * 2 + hi) ^ (lc & 7)) * 8]);
        acc_o[db] = __builtin_amdgcn_mfma_f32_32x32x16_bf16(pa[ks], vb, acc_o[db], 0, 0, 0);
      }
    }
  }

  // epilogue: O[b][s][h*128+d] bf16
  float rl[16];
#pragma unroll
  for (int r = 0; r < 16; ++r) rl[r] = 1.0f / l_r[r];
#pragma unroll
  for (int db = 0; db < 4; ++db)
#pragma unroll
    for (int r = 0; r < 16; ++r) {
      int s_glob = q0 + wid * 32 + (r & 3) + 8 * (r >> 2) + 4 * hi;
      int col = db * 32 + lc;
      O[((size_t)b * S_LEN + s_glob) * EMB + h * HD + col] = f2b(acc_o[db][r] * rl[r]);
    }
}

extern "C" void kernel_launch(void* const* d_in, const int* in_sizes, int n_in,
                              void* d_out, int out_size, void* d_ws, size_t ws_size,
                              hipStream_t stream) {
  const float* xf    = (const float*)d_in[0];
  const float* wckvf = (const float*)d_in[1];
  const float* wkf   = (const float*)d_in[2];
  const float* wvf   = (const float*)d_in[3];
  const float* wcqf  = (const float*)d_in[4];
  const float* wqf   = (const float*)d_in[5];
  const float* wqrf  = (const float*)d_in[6];
  const float* wkrf  = (const float*)d_in[7];
  const float* wof   = (const float*)d_in[8];
  (void)in_sizes; (void)n_in; (void)out_size; (void)ws_size;

  u16* ws = (u16*)d_ws;
  size_t off = 0;
  auto alloc = [&](size_t n) -> u16* { u16* p = ws + off; off += n; return p; };
  u16* XB     = alloc(8388608);   // x bf16 [4096,2048]
  // W1_T group [1088,2048]: wckv rows 0..511, wcq 512..1023, wkr 1024..1087
  u16* WCKV_T = alloc(1048576);
  u16* WCQ_T  = alloc(1048576);
  u16* WKR_T  = alloc(131072);
  // WKV_T group [4096,512]: wk rows 0..2047, wv rows 2048..4095
  u16* WK_T   = alloc(1048576);
  u16* WV_T   = alloc(1048576);
  // WQQR_T group [3072,512]: wq rows 0..2047, wqr rows 2048..3071
  u16* WQ_T   = alloc(1048576);
  u16* WQR_T  = alloc(524288);
  u16* WO_T   = alloc(4194304);   // [2048,2048]
  u16* CC     = alloc(4456448);   // [4096,1088]: ckv | cq | kr
  u16* QR     = alloc(4194304);   // [4096,1024]
  u16* QCAT   = alloc(12582912);  // [B,H,S,192]
  u16* KCAT   = alloc(12582912);
  u16* VT     = alloc(8388608);   // [B,H,128,S]
  u16* AOUT   = alloc(8388608);   // [4096,2048]
  float* COS_T = (float*)alloc(131072);
  float* SIN_T = (float*)alloc(131072);

  // Fused prep: f2b(x) + all weight transposes + rope table. 10912 blocks.
  prep_kernel<<<10912, 256, 0, stream>>>(xf, XB,
                                         wckvf, WCKV_T, wcqf, WCQ_T, wkrf, WKR_T,
                                         wkf, WK_T, wvf, WV_T, wqf, WQ_T,
                                         wqrf, WQR_T, wof, WO_T,
                                         COS_T, SIN_T);

  const float SC = 0.07216878364870323f;  // 1/sqrt(192)
  // G1: x @ [w_ckv | w_cq | w_kr]  -> CC [4096,1088]
  gemm_bt_kernel<0><<<dim3(9, 32),  256, 0, stream>>>(XB, 2048, WCKV_T, CC, nullptr,
                                                      4096, 1088, 2048, 1.0f);
  // G2: c_kv @ [w_k | w_v] -> KCAT + VT
  gemm_bt_kernel<4><<<dim3(32, 32), 256, 0, stream>>>(CC, 1088, WK_T, KCAT, VT,
                                                      4096, 4096, 512, 1.0f);
  // G3: c_q @ [w_q | w_qr] -> QCAT(scaled) + QR
  gemm_bt_kernel<5><<<dim3(24, 32), 256, 0, stream>>>(CC + 512, 1088, WQ_T, QCAT, QR,
                                                      4096, 3072, 512, SC);

  rope_assemble_kernel<<<8192, 256, 0, stream>>>(QR, CC, COS_T, SIN_T, QCAT, KCAT);

  attn_kernel<<<512, 256, 0, stream>>>(QCAT, KCAT, VT, AOUT);

  // G4: attn_out @ w_o -> d_out (fp32)
  gemm_bt_kernel<1><<<dim3(16, 32), 256, 0, stream>>>(AOUT, 2048, WO_T, d_out, nullptr,
                                                      4096, 2048, 2048, 1.0f);
}

// Round 14
// 271.569 us; speedup vs baseline: 1.6663x; 1.6663x over previous
//
#include <hip/hip_runtime.h>

// MLA v3 forward, MI355X/gfx950. Round 14 = consolidation.
// - Attention: round-9 kernel VERBATIM (best measured: 107.7us, VGPR 80,
//   8 waves, QBLK=128, 16x16x32 MFMA). 32x32 experiment abandoned after
//   4 rounds (register live-set cannot reach 2 waves/SIMD).
// - Prep fused into one launch (round-13, proven).
// - GEMMs identical to round 9 (fused by weight concatenation).

typedef unsigned short u16;
typedef __attribute__((ext_vector_type(8))) short s16x8;
typedef __attribute__((ext_vector_type(4))) float f32x4;
typedef __attribute__((ext_vector_type(8))) __bf16 bf16x8;
typedef __attribute__((ext_vector_type(4))) u16 u16x4;

#define S_LEN 2048
#define NH 16
#define HD 128
#define DQK 192
#define EMB 2048

#define GLOAD_LDS16(g, l)                                                      \
  __builtin_amdgcn_global_load_lds(                                            \
      (const __attribute__((address_space(1))) unsigned int*)(g),              \
      (__attribute__((address_space(3))) unsigned int*)(l), 16, 0, 0)

__device__ __forceinline__ u16 f2b(float f) {
  unsigned u = __builtin_bit_cast(unsigned, f);
  u += 0x7FFFu + ((u >> 16) & 1u);           // RNE to bf16
  return (u16)(u >> 16);
}
__device__ __forceinline__ float b2f(u16 v) {
  unsigned u = ((unsigned)v) << 16;
  return __builtin_bit_cast(float, u);
}
__device__ __forceinline__ bf16x8 ld_bf8(const u16* p) {
  return __builtin_bit_cast(bf16x8, *(const s16x8*)p);
}

// Transpose one 64x64 tile: in f32 [K][N] -> out bf16 [N][K].
__device__ __forceinline__ void transpose_tile(const float* __restrict__ in,
                                               u16* __restrict__ out,
                                               int K, int N, int local, int t,
                                               u16* T /* [64*72] LDS */) {
  int nt = N >> 6;
  int n0 = (local % nt) * 64, k0 = (local / nt) * 64;
#pragma unroll
  for (int r = 0; r < 4; ++r) {
    int kl = (t >> 4) + r * 16, nl = (t & 15) * 4;
    f32x4 v = *(const f32x4*)(in + (size_t)(k0 + kl) * N + n0 + nl);
#pragma unroll
    for (int j = 0; j < 4; ++j) T[(nl + j) * 72 + kl] = f2b(v[j]);
  }
  __syncthreads();
#pragma unroll
  for (int r = 0; r < 2; ++r) {
    int chunk = t + r * 256, nr = chunk >> 3, kc = (chunk & 7) * 8;
    *(s16x8*)(out + (size_t)(n0 + nr) * K + k0 + kc) = *(const s16x8*)(&T[nr * 72 + kc]);
  }
}

// Fused prep: [0,8192) f2b(x); then 8 weight transposes; then rope table.
__global__ __launch_bounds__(256) void prep_kernel(
    const float* __restrict__ xf, u16* __restrict__ XB,
    const float* __restrict__ wckvf, u16* __restrict__ WCKV_T,
    const float* __restrict__ wcqf,  u16* __restrict__ WCQ_T,
    const float* __restrict__ wkrf,  u16* __restrict__ WKR_T,
    const float* __restrict__ wkf,   u16* __restrict__ WK_T,
    const float* __restrict__ wvf,   u16* __restrict__ WV_T,
    const float* __restrict__ wqf,   u16* __restrict__ WQ_T,
    const float* __restrict__ wqrf,  u16* __restrict__ WQR_T,
    const float* __restrict__ wof,   u16* __restrict__ WO_T,
    float* __restrict__ cosT, float* __restrict__ sinT) {
  __shared__ u16 T[64 * 72];
  const int id = blockIdx.x, t = threadIdx.x;
  if (id < 8192) {                       // x f32 -> bf16, 4 el/thread
    int i = id * 256 + t;                // n4 = 2097152 exactly
    f32x4 v = *(const f32x4*)(xf + (size_t)i * 4);
    u16x4 o = { f2b(v[0]), f2b(v[1]), f2b(v[2]), f2b(v[3]) };
    *(u16x4*)(XB + (size_t)i * 4) = o;
  } else if (id < 8448)  { transpose_tile(wckvf, WCKV_T, 2048, 512,  id - 8192, t, T); }
  else if (id < 8704)    { transpose_tile(wcqf,  WCQ_T,  2048, 512,  id - 8448, t, T); }
  else if (id < 8736)    { transpose_tile(wkrf,  WKR_T,  2048, 64,   id - 8704, t, T); }
  else if (id < 8992)    { transpose_tile(wkf,   WK_T,   512,  2048, id - 8736, t, T); }
  else if (id < 9248)    { transpose_tile(wvf,   WV_T,   512,  2048, id - 8992, t, T); }
  else if (id < 9504)    { transpose_tile(wqf,   WQ_T,   512,  2048, id - 9248, t, T); }
  else if (id < 9632)    { transpose_tile(wqrf,  WQR_T,  512,  1024, id - 9504, t, T); }
  else if (id < 10656)   { transpose_tile(wof,   WO_T,   2048, 2048, id - 9632, t, T); }
  else {                                 // rope cos/sin table, 65536 entries
    int i2 = (id - 10656) * 256 + t;
    int s = i2 >> 5, i = i2 & 31;
    float inv = exp2f(-(float)i * (13.287712379549449f / 32.0f));
    float ang = (float)s * inv;
    cosT[i2] = cosf(ang);
    sinT[i2] = sinf(ang);
  }
}

// C = A[M,K](lda) @ BT[N,K]^T, bf16 in, fp32 accum. 128x128 tile, BK=64.
// LDS double-buffer, 1 barrier/iter; global_load_lds 16B, source-swizzled.
// MODE 0: bf16 [M,N]->Cout; MODE 1: fp32 [M,N]->Cout;
// MODE 4: col<2048 -> KCAT [b,h,s,192]; col>=2048 -> VT [b,h,d,s];
// MODE 5: col<2048 -> QCAT [b,h,s,192] scaled; col>=2048 -> QR [M,1024].
template<int MODE>
__global__ __launch_bounds__(256) void gemm_bt_kernel(const u16* __restrict__ A,
                                                      int lda,
                                                      const u16* __restrict__ BT,
                                                      void* __restrict__ Cout,
                                                      void* __restrict__ Cout2,
                                                      int M, int N, int K,
                                                      float scale) {
  __shared__ __align__(16) u16 As[2][128 * 64];
  __shared__ __align__(16) u16 Bs[2][128 * 64];
  const int t = threadIdx.x;
  const int lane = t & 63, wid = t >> 6;
  const int wr = (wid >> 1) * 64, wc = (wid & 1) * 64;
  const int bm0 = blockIdx.y * 128, bn0 = blockIdx.x * 128;
  const int lr = lane & 15, lg = lane >> 4;

  auto stage = [&](int k0, int buf) {
#pragma unroll
    for (int r = 0; r < 4; ++r) {
      int chunk = t + r * 256;
      int row = chunk >> 3, kcs = (chunk & 7) * 8;
      int kcg = kcs ^ ((row & 7) << 3);      // inverse swizzle on SOURCE
      GLOAD_LDS16(A + (size_t)(bm0 + row) * lda + k0 + kcg, &As[buf][chunk * 8]);
      GLOAD_LDS16(BT + (size_t)(bn0 + row) * K + k0 + kcg, &Bs[buf][chunk * 8]);
    }
  };

  f32x4 acc[4][4] = {};
  const int nt = K >> 6;
  stage(0, 0);
  for (int tk = 0; tk < nt; ++tk) {
    const int cur = tk & 1;
    __syncthreads();
    if (tk + 1 < nt) stage((tk + 1) << 6, cur ^ 1);
#pragma unroll
    for (int kk = 0; kk < 2; ++kk) {
      bf16x8 af[4], bfr[4];
      const int kbase = kk * 32 + lg * 8;
#pragma unroll
      for (int m = 0; m < 4; ++m) {
        int row = wr + m * 16 + lr;
        af[m] = ld_bf8(&As[cur][row * 64 + (kbase ^ ((row & 7) << 3))]);
      }
#pragma unroll
      for (int n = 0; n < 4; ++n) {
        int row = wc + n * 16 + lr;
        bfr[n] = ld_bf8(&Bs[cur][row * 64 + (kbase ^ ((row & 7) << 3))]);
      }
#pragma unroll
      for (int m = 0; m < 4; ++m)
#pragma unroll
        for (int n = 0; n < 4; ++n)
          acc[m][n] = __builtin_amdgcn_mfma_f32_16x16x32_bf16(af[m], bfr[n], acc[m][n], 0, 0, 0);
    }
  }

  // C/D layout: col = lane&15, row = (lane>>4)*4 + reg
#pragma unroll
  for (int m = 0; m < 4; ++m)
#pragma unroll
    for (int n = 0; n < 4; ++n)
#pragma unroll
      for (int rg = 0; rg < 4; ++rg) {
        int row = bm0 + wr + m * 16 + lg * 4 + rg;
        int col = bn0 + wc + n * 16 + lr;
        if (col >= N) continue;
        float v = acc[m][n][rg];
        if (MODE == 0) {
          ((u16*)Cout)[(size_t)row * N + col] = f2b(v * scale);
        } else if (MODE == 1) {
          ((float*)Cout)[(size_t)row * N + col] = v * scale;
        } else if (MODE == 4) {
          int bb = row >> 11, s = row & 2047;
          if (col < 2048) {
            int h = col >> 7, d = col & 127;
            ((u16*)Cout)[((size_t)(bb * NH + h) * S_LEN + s) * DQK + d] = f2b(v);
          } else {
            int c2 = col - 2048, h = c2 >> 7, d = c2 & 127;
            ((u16*)Cout2)[((size_t)(bb * NH + h) * HD + d) * S_LEN + s] = f2b(v);
          }
        } else {  // MODE 5
          int bb = row >> 11, s = row & 2047;
          if (col < 2048) {
            int h = col >> 7, d = col & 127;
            ((u16*)Cout)[((size_t)(bb * NH + h) * S_LEN + s) * DQK + d] = f2b(v * scale);
          } else {
            ((u16*)Cout2)[(size_t)row * 1024 + (col - 2048)] = f2b(v);
          }
        }
      }
}

// Fill rope halves of Qcat/Kcat. kr lives in CC cols 1024..1087 (stride 1088).
__global__ __launch_bounds__(256) void rope_assemble_kernel(const u16* __restrict__ qr,
                                                            const u16* __restrict__ cc,
                                                            const float* __restrict__ cosT,
                                                            const float* __restrict__ sinT,
                                                            u16* __restrict__ Qcat,
                                                            u16* __restrict__ Kcat) {
  int id = blockIdx.x * 256 + threadIdx.x;   // B*H*S*32 = 2^21
  int i = id & 31;
  int s = (id >> 5) & 2047;
  int h = (id >> 16) & 15;
  int b = id >> 20;
  float c = cosT[(s << 5) + i], sn = sinT[(s << 5) + i];
  const float SC = 0.07216878364870323f;     // 1/sqrt(192)

  size_t qbase = ((size_t)b * S_LEN + s) * 1024 + h * 64 + 2 * i;
  float qe = b2f(qr[qbase]), qo = b2f(qr[qbase + 1]);
  size_t obase = ((size_t)(b * NH + h) * S_LEN + s) * DQK + HD + 2 * i;
  Qcat[obase]     = f2b((qe * c - qo * sn) * SC);
  Qcat[obase + 1] = f2b((qe * sn + qo * c) * SC);

  size_t kbase = ((size_t)b * S_LEN + s) * 1088 + 1024 + 2 * i;
  float ke = b2f(cc[kbase]), ko = b2f(cc[kbase + 1]);
  Kcat[obase]     = f2b(ke * c - ko * sn);
  Kcat[obase + 1] = f2b(ke * sn + ko * c);
}

// Flash attention, causal. Round-9 kernel (8 waves, QBLK=128, kv tile 64).
// Grid = 512 flat blocks; balanced decode (p8<8 -> qb=p8 ; else 23-p8).
__global__ __launch_bounds__(512, 2) void attn_kernel(const u16* __restrict__ Q,
                                                      const u16* __restrict__ K,
                                                      const u16* __restrict__ VT,
                                                      u16* __restrict__ O) {
  __shared__ u16 Ks[64 * 200];    // [kv][d0..191]
  __shared__ u16 Vs[128 * 72];    // [d][kv0..63]
  __shared__ u16 Ps[8 * 16 * 88]; // per-wave [q][kv]
  const int id = blockIdx.x;
  const int p8 = id >> 5, hb = id & 31;
  const int h = hb & 15, b = hb >> 4;
  const int qb = (p8 < 8) ? p8 : 23 - p8;
  const int q0 = qb * 128;
  const int t = threadIdx.x, lane = t & 63, wid = t >> 6;
  const int lr = lane & 15, lg = lane >> 4;
  const size_t qk_head = (size_t)(b * NH + h) * S_LEN * DQK;
  const size_t vt_head = (size_t)(b * NH + h) * HD * S_LEN;

  s16x8 kst[3], vst[2];
  auto gload = [&](int kt) {
#pragma unroll
    for (int r = 0; r < 3; ++r) {
      int chunk = t + r * 512, row = chunk / 24, cc = chunk % 24;
      kst[r] = *(const s16x8*)(K + qk_head + (size_t)(kt * 64 + row) * DQK + cc * 8);
    }
#pragma unroll
    for (int r = 0; r < 2; ++r) {
      int chunk = t + r * 512, d = chunk >> 3, cc = chunk & 7;
      vst[r] = *(const s16x8*)(VT + vt_head + (size_t)d * S_LEN + kt * 64 + cc * 8);
    }
  };
  auto swr = [&]() {
#pragma unroll
    for (int r = 0; r < 3; ++r) {
      int chunk = t + r * 512, row = chunk / 24, cc = chunk % 24;
      *(s16x8*)(&Ks[row * 200 + cc * 8]) = kst[r];
    }
#pragma unroll
    for (int r = 0; r < 2; ++r) {
      int chunk = t + r * 512, d = chunk >> 3, cc = chunk & 7;
      *(s16x8*)(&Vs[d * 72 + cc * 8]) = vst[r];
    }
  };

  bf16x8 qa[6];
  {
    const u16* qrow = Q + qk_head + (size_t)(q0 + wid * 16 + lr) * DQK;
#pragma unroll
    for (int ks = 0; ks < 6; ++ks) qa[ks] = ld_bf8(qrow + ks * 32 + lg * 8);
  }

  f32x4 acc_o[8] = {};
  float m_r[4] = { -INFINITY, -INFINITY, -INFINITY, -INFINITY };
  float l_r[4] = { 0.f, 0.f, 0.f, 0.f };

  const int nt = 2 * qb + 2;
  gload(0);
#pragma unroll 1
  for (int kt = 0; kt < nt; ++kt) {
    __syncthreads();                 // all waves done reading previous tile
    swr();                           // stage tile kt
    if (kt + 1 < nt) gload(kt + 1);  // prefetch next
    __syncthreads();                 // tile kt visible

    f32x4 sacc[4];
#pragma unroll
    for (int cb = 0; cb < 4; ++cb) {
      f32x4 sv = {};
#pragma unroll
      for (int ks = 0; ks < 6; ++ks) {
        bf16x8 kb = ld_bf8(&Ks[(cb * 16 + lr) * 200 + ks * 32 + lg * 8]);
        sv = __builtin_amdgcn_mfma_f32_16x16x32_bf16(qa[ks], kb, sv, 0, 0, 0);
      }
      sacc[cb] = sv;
    }

    if (kt >= 2 * qb) {              // diagonal tiles: causal mask
#pragma unroll
      for (int cb = 0; cb < 4; ++cb)
#pragma unroll
        for (int rg = 0; rg < 4; ++rg) {
          int q_g = q0 + wid * 16 + lg * 4 + rg;
          int kv_g = kt * 64 + cb * 16 + lr;
          if (kv_g > q_g) sacc[cb][rg] = -INFINITY;
        }
    }

    float pmax[4];
#pragma unroll
    for (int rg = 0; rg < 4; ++rg)
      pmax[rg] = fmaxf(fmaxf(sacc[0][rg], sacc[1][rg]), fmaxf(sacc[2][rg], sacc[3][rg]));
#pragma unroll
    for (int off = 1; off < 16; off <<= 1)
#pragma unroll
      for (int rg = 0; rg < 4; ++rg)
        pmax[rg] = fmaxf(pmax[rg], __shfl_xor(pmax[rg], off, 64));

    float alpha[4];
#pragma unroll
    for (int rg = 0; rg < 4; ++rg) {
      float mn = fmaxf(m_r[rg], pmax[rg]);
      alpha[rg] = __expf(m_r[rg] - mn);
      m_r[rg] = mn;
      l_r[rg] *= alpha[rg];
    }
#pragma unroll
    for (int vb = 0; vb < 8; ++vb)
#pragma unroll
      for (int rg = 0; rg < 4; ++rg)
        acc_o[vb][rg] *= alpha[rg];

    float psum[4] = { 0.f, 0.f, 0.f, 0.f };
#pragma unroll
    for (int cb = 0; cb < 4; ++cb)
#pragma unroll
      for (int rg = 0; rg < 4; ++rg) {
        float pv = __expf(sacc[cb][rg] - m_r[rg]);
        sacc[cb][rg] = pv;
        psum[rg] += pv;
      }
#pragma unroll
    for (int off = 1; off < 16; off <<= 1)
#pragma unroll
      for (int rg = 0; rg < 4; ++rg)
        psum[rg] += __shfl_xor(psum[rg], off, 64);
#pragma unroll
    for (int rg = 0; rg < 4; ++rg) l_r[rg] += psum[rg];

    // P -> per-wave LDS (same-wave RAW only)
    u16* psw = &Ps[wid * (16 * 88)];
#pragma unroll
    for (int cb = 0; cb < 4; ++cb)
#pragma unroll
      for (int rg = 0; rg < 4; ++rg)
        psw[(lg * 4 + rg) * 88 + cb * 16 + lr] = f2b(sacc[cb][rg]);

    bf16x8 pa[2];
#pragma unroll
    for (int ks = 0; ks < 2; ++ks) pa[ks] = ld_bf8(&psw[lr * 88 + ks * 32 + lg * 8]);
#pragma unroll
    for (int vb = 0; vb < 8; ++vb) {
#pragma unroll
      for (int ks = 0; ks < 2; ++ks) {
        bf16x8 vv = ld_bf8(&Vs[(vb * 16 + lr) * 72 + ks * 32 + lg * 8]);
        acc_o[vb] = __builtin_amdgcn_mfma_f32_16x16x32_bf16(pa[ks], vv, acc_o[vb], 0, 0, 0);
      }
    }
  }

  // epilogue: O[b][s][h*128+d] bf16
#pragma unroll
  for (int vb = 0; vb < 8; ++vb)
#pragma unroll
    for (int rg = 0; rg < 4; ++rg) {
      int s_glob = q0 + wid * 16 + lg * 4 + rg;
      int col = vb * 16 + lr;
      O[((size_t)b * S_LEN + s_glob) * EMB + h * HD + col] = f2b(acc_o[vb][rg] / l_r[rg]);
    }
}

extern "C" void kernel_launch(void* const* d_in, const int* in_sizes, int n_in,
                              void* d_out, int out_size, void* d_ws, size_t ws_size,
                              hipStream_t stream) {
  const float* xf    = (const float*)d_in[0];
  const float* wckvf = (const float*)d_in[1];
  const float* wkf   = (const float*)d_in[2];
  const float* wvf   = (const float*)d_in[3];
  const float* wcqf  = (const float*)d_in[4];
  const float* wqf   = (const float*)d_in[5];
  const float* wqrf  = (const float*)d_in[6];
  const float* wkrf  = (const float*)d_in[7];
  const float* wof   = (const float*)d_in[8];
  (void)in_sizes; (void)n_in; (void)out_size; (void)ws_size;

  u16* ws = (u16*)d_ws;
  size_t off = 0;
  auto alloc = [&](size_t n) -> u16* { u16* p = ws + off; off += n; return p; };
  u16* XB     = alloc(8388608);   // x bf16 [4096,2048]
  // W1_T group [1088,2048]: wckv rows 0..511, wcq 512..1023, wkr 1024..1087
  u16* WCKV_T = alloc(1048576);
  u16* WCQ_T  = alloc(1048576);
  u16* WKR_T  = alloc(131072);
  // WKV_T group [4096,512]: wk rows 0..2047, wv rows 2048..4095
  u16* WK_T   = alloc(1048576);
  u16* WV_T   = alloc(1048576);
  // WQQR_T group [3072,512]: wq rows 0..2047, wqr rows 2048..3071
  u16* WQ_T   = alloc(1048576);
  u16* WQR_T  = alloc(524288);
  u16* WO_T   = alloc(4194304);   // [2048,2048]
  u16* CC     = alloc(4456448);   // [4096,1088]: ckv | cq | kr
  u16* QR     = alloc(4194304);   // [4096,1024]
  u16* QCAT   = alloc(12582912);  // [B,H,S,192]
  u16* KCAT   = alloc(12582912);
  u16* VT     = alloc(8388608);   // [B,H,128,S]
  u16* AOUT   = alloc(8388608);   // [4096,2048]
  float* COS_T = (float*)alloc(131072);
  float* SIN_T = (float*)alloc(131072);

  // Fused prep: f2b(x) + all weight transposes + rope table.
  prep_kernel<<<10912, 256, 0, stream>>>(xf, XB,
                                         wckvf, WCKV_T, wcqf, WCQ_T, wkrf, WKR_T,
                                         wkf, WK_T, wvf, WV_T, wqf, WQ_T,
                                         wqrf, WQR_T, wof, WO_T,
                                         COS_T, SIN_T);

  const float SC = 0.07216878364870323f;  // 1/sqrt(192)
  // G1: x @ [w_ckv | w_cq | w_kr]  -> CC [4096,1088]
  gemm_bt_kernel<0><<<dim3(9, 32),  256, 0, stream>>>(XB, 2048, WCKV_T, CC, nullptr,
                                                      4096, 1088, 2048, 1.0f);
  // G2: c_kv @ [w_k | w_v] -> KCAT + VT
  gemm_bt_kernel<4><<<dim3(32, 32), 256, 0, stream>>>(CC, 1088, WK_T, KCAT, VT,
                                                      4096, 4096, 512, 1.0f);
  // G3: c_q @ [w_q | w_qr] -> QCAT(scaled) + QR
  gemm_bt_kernel<5><<<dim3(24, 32), 256, 0, stream>>>(CC + 512, 1088, WQ_T, QCAT, QR,
                                                      4096, 3072, 512, SC);

  rope_assemble_kernel<<<8192, 256, 0, stream>>>(QR, CC, COS_T, SIN_T, QCAT, KCAT);

  attn_kernel<<<512, 512, 0, stream>>>(QCAT, KCAT, VT, AOUT);

  // G4: attn_out @ w_o -> d_out (fp32)
  gemm_bt_kernel<1><<<dim3(16, 32), 256, 0, stream>>>(AOUT, 2048, WO_T, d_out, nullptr,
                                                      4096, 2048, 2048, 1.0f);
}

// Round 15
// 270.951 us; speedup vs baseline: 1.6701x; 1.0023x over previous
//
#include <hip/hip_runtime.h>

// MLA v3 forward, MI355X/gfx950. Round 15.
// vs round 14: (1) G2+G3 fused into ONE GEMM launch (MODE 6, N=7168 over
// the adjacent wk|wv|wq|wqr weight block, A-offset by bn0); (2) all GEMMs
// use 1D grid + XCD-chunked swizzle (T1) for per-XCD L2 A-panel reuse;
// (3) attn adds defer-max (T13, THR=8). Attn core = round-9 (proven).

typedef unsigned short u16;
typedef __attribute__((ext_vector_type(8))) short s16x8;
typedef __attribute__((ext_vector_type(4))) float f32x4;
typedef __attribute__((ext_vector_type(8))) __bf16 bf16x8;
typedef __attribute__((ext_vector_type(4))) u16 u16x4;

#define S_LEN 2048
#define NH 16
#define HD 128
#define DQK 192
#define EMB 2048

#define GLOAD_LDS16(g, l)                                                      \
  __builtin_amdgcn_global_load_lds(                                            \
      (const __attribute__((address_space(1))) unsigned int*)(g),              \
      (__attribute__((address_space(3))) unsigned int*)(l), 16, 0, 0)

__device__ __forceinline__ u16 f2b(float f) {
  unsigned u = __builtin_bit_cast(unsigned, f);
  u += 0x7FFFu + ((u >> 16) & 1u);           // RNE to bf16
  return (u16)(u >> 16);
}
__device__ __forceinline__ float b2f(u16 v) {
  unsigned u = ((unsigned)v) << 16;
  return __builtin_bit_cast(float, u);
}
__device__ __forceinline__ bf16x8 ld_bf8(const u16* p) {
  return __builtin_bit_cast(bf16x8, *(const s16x8*)p);
}

// Transpose one 64x64 tile: in f32 [K][N] -> out bf16 [N][K].
__device__ __forceinline__ void transpose_tile(const float* __restrict__ in,
                                               u16* __restrict__ out,
                                               int K, int N, int local, int t,
                                               u16* T /* [64*72] LDS */) {
  int nt = N >> 6;
  int n0 = (local % nt) * 64, k0 = (local / nt) * 64;
#pragma unroll
  for (int r = 0; r < 4; ++r) {
    int kl = (t >> 4) + r * 16, nl = (t & 15) * 4;
    f32x4 v = *(const f32x4*)(in + (size_t)(k0 + kl) * N + n0 + nl);
#pragma unroll
    for (int j = 0; j < 4; ++j) T[(nl + j) * 72 + kl] = f2b(v[j]);
  }
  __syncthreads();
#pragma unroll
  for (int r = 0; r < 2; ++r) {
    int chunk = t + r * 256, nr = chunk >> 3, kc = (chunk & 7) * 8;
    *(s16x8*)(out + (size_t)(n0 + nr) * K + k0 + kc) = *(const s16x8*)(&T[nr * 72 + kc]);
  }
}

// Fused prep: [0,8192) f2b(x); then 8 weight transposes; then rope table.
__global__ __launch_bounds__(256) void prep_kernel(
    const float* __restrict__ xf, u16* __restrict__ XB,
    const float* __restrict__ wckvf, u16* __restrict__ WCKV_T,
    const float* __restrict__ wcqf,  u16* __restrict__ WCQ_T,
    const float* __restrict__ wkrf,  u16* __restrict__ WKR_T,
    const float* __restrict__ wkf,   u16* __restrict__ WK_T,
    const float* __restrict__ wvf,   u16* __restrict__ WV_T,
    const float* __restrict__ wqf,   u16* __restrict__ WQ_T,
    const float* __restrict__ wqrf,  u16* __restrict__ WQR_T,
    const float* __restrict__ wof,   u16* __restrict__ WO_T,
    float* __restrict__ cosT, float* __restrict__ sinT) {
  __shared__ u16 T[64 * 72];
  const int id = blockIdx.x, t = threadIdx.x;
  if (id < 8192) {                       // x f32 -> bf16, 4 el/thread
    int i = id * 256 + t;                // n4 = 2097152 exactly
    f32x4 v = *(const f32x4*)(xf + (size_t)i * 4);
    u16x4 o = { f2b(v[0]), f2b(v[1]), f2b(v[2]), f2b(v[3]) };
    *(u16x4*)(XB + (size_t)i * 4) = o;
  } else if (id < 8448)  { transpose_tile(wckvf, WCKV_T, 2048, 512,  id - 8192, t, T); }
  else if (id < 8704)    { transpose_tile(wcqf,  WCQ_T,  2048, 512,  id - 8448, t, T); }
  else if (id < 8736)    { transpose_tile(wkrf,  WKR_T,  2048, 64,   id - 8704, t, T); }
  else if (id < 8992)    { transpose_tile(wkf,   WK_T,   512,  2048, id - 8736, t, T); }
  else if (id < 9248)    { transpose_tile(wvf,   WV_T,   512,  2048, id - 8992, t, T); }
  else if (id < 9504)    { transpose_tile(wqf,   WQ_T,   512,  2048, id - 9248, t, T); }
  else if (id < 9632)    { transpose_tile(wqrf,  WQR_T,  512,  1024, id - 9504, t, T); }
  else if (id < 10656)   { transpose_tile(wof,   WO_T,   2048, 2048, id - 9632, t, T); }
  else {                                 // rope cos/sin table, 65536 entries
    int i2 = (id - 10656) * 256 + t;
    int s = i2 >> 5, i = i2 & 31;
    float inv = exp2f(-(float)i * (13.287712379549449f / 32.0f));
    float ang = (float)s * inv;
    cosT[i2] = cosf(ang);
    sinT[i2] = sinf(ang);
  }
}

// C = A[M,K](lda) @ BT[N,K]^T, bf16 in, fp32 accum. 128x128 tile, BK=64.
// 1D grid + XCD-chunked swizzle (gridDim.x % 8 == 0 required).
// LDS double-buffer, 1 barrier/iter; global_load_lds 16B, source-swizzled.
// MODE 0: bf16 [M,N]->C0; MODE 1: fp32 [M,N]->C0;
// MODE 6 (fused G2+G3, N=7168, bn0>=4096 uses A+512):
//   col<2048 -> KCAT(C0)[b,h,s,192]; col<4096 -> VT(C1)[b,h,d,s];
//   col<6144 -> QCAT(C2)[b,h,s,192]*scale; else -> QR(C3)[M,1024].
template<int MODE>
__global__ __launch_bounds__(256) void gemm_bt_kernel(const u16* __restrict__ A,
                                                      int lda,
                                                      const u16* __restrict__ BT,
                                                      void* __restrict__ C0,
                                                      void* __restrict__ C1,
                                                      void* __restrict__ C2,
                                                      void* __restrict__ C3,
                                                      int M, int N, int K,
                                                      int nx, float scale) {
  __shared__ __align__(16) u16 As[2][128 * 64];
  __shared__ __align__(16) u16 Bs[2][128 * 64];
  const int t = threadIdx.x;
  const int lane = t & 63, wid = t >> 6;
  const int wr = (wid >> 1) * 64, wc = (wid & 1) * 64;
  // XCD-chunked swizzle: round-robin -> contiguous chunk per XCD.
  const int cpx = gridDim.x >> 3;
  int wg = blockIdx.x;
  wg = (wg & 7) * cpx + (wg >> 3);
  const int bn0 = (wg % nx) * 128;
  const int bm0 = (wg / nx) * 128;
  if (MODE == 6 && bn0 >= 4096) A += 512;   // G3 part reads c_q slice
  const int lr = lane & 15, lg = lane >> 4;

  auto stage = [&](int k0, int buf) {
#pragma unroll
    for (int r = 0; r < 4; ++r) {
      int chunk = t + r * 256;
      int row = chunk >> 3, kcs = (chunk & 7) * 8;
      int kcg = kcs ^ ((row & 7) << 3);      // inverse swizzle on SOURCE
      GLOAD_LDS16(A + (size_t)(bm0 + row) * lda + k0 + kcg, &As[buf][chunk * 8]);
      GLOAD_LDS16(BT + (size_t)(bn0 + row) * K + k0 + kcg, &Bs[buf][chunk * 8]);
    }
  };

  f32x4 acc[4][4] = {};
  const int nt = K >> 6;
  stage(0, 0);
  for (int tk = 0; tk < nt; ++tk) {
    const int cur = tk & 1;
    __syncthreads();
    if (tk + 1 < nt) stage((tk + 1) << 6, cur ^ 1);
#pragma unroll
    for (int kk = 0; kk < 2; ++kk) {
      bf16x8 af[4], bfr[4];
      const int kbase = kk * 32 + lg * 8;
#pragma unroll
      for (int m = 0; m < 4; ++m) {
        int row = wr + m * 16 + lr;
        af[m] = ld_bf8(&As[cur][row * 64 + (kbase ^ ((row & 7) << 3))]);
      }
#pragma unroll
      for (int n = 0; n < 4; ++n) {
        int row = wc + n * 16 + lr;
        bfr[n] = ld_bf8(&Bs[cur][row * 64 + (kbase ^ ((row & 7) << 3))]);
      }
#pragma unroll
      for (int m = 0; m < 4; ++m)
#pragma unroll
        for (int n = 0; n < 4; ++n)
          acc[m][n] = __builtin_amdgcn_mfma_f32_16x16x32_bf16(af[m], bfr[n], acc[m][n], 0, 0, 0);
    }
  }

  // C/D layout: col = lane&15, row = (lane>>4)*4 + reg
#pragma unroll
  for (int m = 0; m < 4; ++m)
#pragma unroll
    for (int n = 0; n < 4; ++n)
#pragma unroll
      for (int rg = 0; rg < 4; ++rg) {
        int row = bm0 + wr + m * 16 + lg * 4 + rg;
        int col = bn0 + wc + n * 16 + lr;
        if (col >= N) continue;
        float v = acc[m][n][rg];
        if (MODE == 0) {
          ((u16*)C0)[(size_t)row * N + col] = f2b(v * scale);
        } else if (MODE == 1) {
          ((float*)C0)[(size_t)row * N + col] = v * scale;
        } else {  // MODE 6
          int bb = row >> 11, s = row & 2047;
          if (col < 2048) {
            int h = col >> 7, d = col & 127;
            ((u16*)C0)[((size_t)(bb * NH + h) * S_LEN + s) * DQK + d] = f2b(v);
          } else if (col < 4096) {
            int c2 = col - 2048, h = c2 >> 7, d = c2 & 127;
            ((u16*)C1)[((size_t)(bb * NH + h) * HD + d) * S_LEN + s] = f2b(v);
          } else if (col < 6144) {
            int c3 = col - 4096, h = c3 >> 7, d = c3 & 127;
            ((u16*)C2)[((size_t)(bb * NH + h) * S_LEN + s) * DQK + d] = f2b(v * scale);
          } else {
            ((u16*)C3)[(size_t)row * 1024 + (col - 6144)] = f2b(v);
          }
        }
      }
}

// Fill rope halves of Qcat/Kcat. kr lives in CC cols 1024..1087 (stride 1088).
__global__ __launch_bounds__(256) void rope_assemble_kernel(const u16* __restrict__ qr,
                                                            const u16* __restrict__ cc,
                                                            const float* __restrict__ cosT,
                                                            const float* __restrict__ sinT,
                                                            u16* __restrict__ Qcat,
                                                            u16* __restrict__ Kcat) {
  int id = blockIdx.x * 256 + threadIdx.x;   // B*H*S*32 = 2^21
  int i = id & 31;
  int s = (id >> 5) & 2047;
  int h = (id >> 16) & 15;
  int b = id >> 20;
  float c = cosT[(s << 5) + i], sn = sinT[(s << 5) + i];
  const float SC = 0.07216878364870323f;     // 1/sqrt(192)

  size_t qbase = ((size_t)b * S_LEN + s) * 1024 + h * 64 + 2 * i;
  float qe = b2f(qr[qbase]), qo = b2f(qr[qbase + 1]);
  size_t obase = ((size_t)(b * NH + h) * S_LEN + s) * DQK + HD + 2 * i;
  Qcat[obase]     = f2b((qe * c - qo * sn) * SC);
  Qcat[obase + 1] = f2b((qe * sn + qo * c) * SC);

  size_t kbase = ((size_t)b * S_LEN + s) * 1088 + 1024 + 2 * i;
  float ke = b2f(cc[kbase]), ko = b2f(cc[kbase + 1]);
  Kcat[obase]     = f2b(ke * c - ko * sn);
  Kcat[obase + 1] = f2b(ke * sn + ko * c);
}

// Flash attention, causal. Round-9 kernel + defer-max (T13, THR=8).
// 8 waves, QBLK=128, kv tile 64. Grid 512; balanced decode.
__global__ __launch_bounds__(512, 2) void attn_kernel(const u16* __restrict__ Q,
                                                      const u16* __restrict__ K,
                                                      const u16* __restrict__ VT,
                                                      u16* __restrict__ O) {
  __shared__ u16 Ks[64 * 200];    // [kv][d0..191]
  __shared__ u16 Vs[128 * 72];    // [d][kv0..63]
  __shared__ u16 Ps[8 * 16 * 88]; // per-wave [q][kv]
  const int id = blockIdx.x;
  const int p8 = id >> 5, hb = id & 31;
  const int h = hb & 15, b = hb >> 4;
  const int qb = (p8 < 8) ? p8 : 23 - p8;
  const int q0 = qb * 128;
  const int t = threadIdx.x, lane = t & 63, wid = t >> 6;
  const int lr = lane & 15, lg = lane >> 4;
  const size_t qk_head = (size_t)(b * NH + h) * S_LEN * DQK;
  const size_t vt_head = (size_t)(b * NH + h) * HD * S_LEN;

  s16x8 kst[3], vst[2];
  auto gload = [&](int kt) {
#pragma unroll
    for (int r = 0; r < 3; ++r) {
      int chunk = t + r * 512, row = chunk / 24, cc = chunk % 24;
      kst[r] = *(const s16x8*)(K + qk_head + (size_t)(kt * 64 + row) * DQK + cc * 8);
    }
#pragma unroll
    for (int r = 0; r < 2; ++r) {
      int chunk = t + r * 512, d = chunk >> 3, cc = chunk & 7;
      vst[r] = *(const s16x8*)(VT + vt_head + (size_t)d * S_LEN + kt * 64 + cc * 8);
    }
  };
  auto swr = [&]() {
#pragma unroll
    for (int r = 0; r < 3; ++r) {
      int chunk = t + r * 512, row = chunk / 24, cc = chunk % 24;
      *(s16x8*)(&Ks[row * 200 + cc * 8]) = kst[r];
    }
#pragma unroll
    for (int r = 0; r < 2; ++r) {
      int chunk = t + r * 512, d = chunk >> 3, cc = chunk & 7;
      *(s16x8*)(&Vs[d * 72 + cc * 8]) = vst[r];
    }
  };

  bf16x8 qa[6];
  {
    const u16* qrow = Q + qk_head + (size_t)(q0 + wid * 16 + lr) * DQK;
#pragma unroll
    for (int ks = 0; ks < 6; ++ks) qa[ks] = ld_bf8(qrow + ks * 32 + lg * 8);
  }

  f32x4 acc_o[8] = {};
  float m_r[4] = { -INFINITY, -INFINITY, -INFINITY, -INFINITY };
  float l_r[4] = { 0.f, 0.f, 0.f, 0.f };

  const int nt = 2 * qb + 2;
  gload(0);
#pragma unroll 1
  for (int kt = 0; kt < nt; ++kt) {
    __syncthreads();                 // all waves done reading previous tile
    swr();                           // stage tile kt
    if (kt + 1 < nt) gload(kt + 1);  // prefetch next
    __syncthreads();                 // tile kt visible

    f32x4 sacc[4];
#pragma unroll
    for (int cb = 0; cb < 4; ++cb) {
      f32x4 sv = {};
#pragma unroll
      for (int ks = 0; ks < 6; ++ks) {
        bf16x8 kb = ld_bf8(&Ks[(cb * 16 + lr) * 200 + ks * 32 + lg * 8]);
        sv = __builtin_amdgcn_mfma_f32_16x16x32_bf16(qa[ks], kb, sv, 0, 0, 0);
      }
      sacc[cb] = sv;
    }

    if (kt >= 2 * qb) {              // diagonal tiles: causal mask
#pragma unroll
      for (int cb = 0; cb < 4; ++cb)
#pragma unroll
        for (int rg = 0; rg < 4; ++rg) {
          int q_g = q0 + wid * 16 + lg * 4 + rg;
          int kv_g = kt * 64 + cb * 16 + lr;
          if (kv_g > q_g) sacc[cb][rg] = -INFINITY;
        }
    }

    float pmax[4];
#pragma unroll
    for (int rg = 0; rg < 4; ++rg)
      pmax[rg] = fmaxf(fmaxf(sacc[0][rg], sacc[1][rg]), fmaxf(sacc[2][rg], sacc[3][rg]));
#pragma unroll
    for (int off = 1; off < 16; off <<= 1)
#pragma unroll
      for (int rg = 0; rg < 4; ++rg)
        pmax[rg] = fmaxf(pmax[rg], __shfl_xor(pmax[rg], off, 64));

    // defer-max (T13): skip O-rescale when per-tile max growth <= 8.
    int nochange = (pmax[0] <= m_r[0] + 8.f) & (pmax[1] <= m_r[1] + 8.f) &
                   (pmax[2] <= m_r[2] + 8.f) & (pmax[3] <= m_r[3] + 8.f);
    if (!__all(nochange)) {
      float alpha[4];
#pragma unroll
      for (int rg = 0; rg < 4; ++rg) {
        float mn = fmaxf(m_r[rg], pmax[rg]);
        alpha[rg] = __expf(m_r[rg] - mn);
        m_r[rg] = mn;
        l_r[rg] *= alpha[rg];
      }
#pragma unroll
      for (int vb = 0; vb < 8; ++vb)
#pragma unroll
        for (int rg = 0; rg < 4; ++rg)
          acc_o[vb][rg] *= alpha[rg];
    }

    float psum[4] = { 0.f, 0.f, 0.f, 0.f };
#pragma unroll
    for (int cb = 0; cb < 4; ++cb)
#pragma unroll
      for (int rg = 0; rg < 4; ++rg) {
        float pv = __expf(sacc[cb][rg] - m_r[rg]);
        sacc[cb][rg] = pv;
        psum[rg] += pv;
      }
#pragma unroll
    for (int off = 1; off < 16; off <<= 1)
#pragma unroll
      for (int rg = 0; rg < 4; ++rg)
        psum[rg] += __shfl_xor(psum[rg], off, 64);
#pragma unroll
    for (int rg = 0; rg < 4; ++rg) l_r[rg] += psum[rg];

    // P -> per-wave LDS (same-wave RAW only)
    u16* psw = &Ps[wid * (16 * 88)];
#pragma unroll
    for (int cb = 0; cb < 4; ++cb)
#pragma unroll
      for (int rg = 0; rg < 4; ++rg)
        psw[(lg * 4 + rg) * 88 + cb * 16 + lr] = f2b(sacc[cb][rg]);

    bf16x8 pa[2];
#pragma unroll
    for (int ks = 0; ks < 2; ++ks) pa[ks] = ld_bf8(&psw[lr * 88 + ks * 32 + lg * 8]);
#pragma unroll
    for (int vb = 0; vb < 8; ++vb) {
#pragma unroll
      for (int ks = 0; ks < 2; ++ks) {
        bf16x8 vv = ld_bf8(&Vs[(vb * 16 + lr) * 72 + ks * 32 + lg * 8]);
        acc_o[vb] = __builtin_amdgcn_mfma_f32_16x16x32_bf16(pa[ks], vv, acc_o[vb], 0, 0, 0);
      }
    }
  }

  // epilogue: O[b][s][h*128+d] bf16
#pragma unroll
  for (int vb = 0; vb < 8; ++vb)
#pragma unroll
    for (int rg = 0; rg < 4; ++rg) {
      int s_glob = q0 + wid * 16 + lg * 4 + rg;
      int col = vb * 16 + lr;
      O[((size_t)b * S_LEN + s_glob) * EMB + h * HD + col] = f2b(acc_o[vb][rg] / l_r[rg]);
    }
}

extern "C" void kernel_launch(void* const* d_in, const int* in_sizes, int n_in,
                              void* d_out, int out_size, void* d_ws, size_t ws_size,
                              hipStream_t stream) {
  const float* xf    = (const float*)d_in[0];
  const float* wckvf = (const float*)d_in[1];
  const float* wkf   = (const float*)d_in[2];
  const float* wvf   = (const float*)d_in[3];
  const float* wcqf  = (const float*)d_in[4];
  const float* wqf   = (const float*)d_in[5];
  const float* wqrf  = (const float*)d_in[6];
  const float* wkrf  = (const float*)d_in[7];
  const float* wof   = (const float*)d_in[8];
  (void)in_sizes; (void)n_in; (void)out_size; (void)ws_size;

  u16* ws = (u16*)d_ws;
  size_t off = 0;
  auto alloc = [&](size_t n) -> u16* { u16* p = ws + off; off += n; return p; };
  u16* XB     = alloc(8388608);   // x bf16 [4096,2048]
  // W1_T group [1088,2048]: wckv rows 0..511, wcq 512..1023, wkr 1024..1087
  u16* WCKV_T = alloc(1048576);
  u16* WCQ_T  = alloc(1048576);
  u16* WKR_T  = alloc(131072);
  // Fused weight block [7168,512]: wk 0..2047 | wv 2048..4095 | wq 4096..6143 | wqr 6144..7167
  u16* WK_T   = alloc(1048576);
  u16* WV_T   = alloc(1048576);
  u16* WQ_T   = alloc(1048576);
  u16* WQR_T  = alloc(524288);
  u16* WO_T   = alloc(4194304);   // [2048,2048]
  u16* CC     = alloc(4456448);   // [4096,1088]: ckv | cq | kr
  u16* QR     = alloc(4194304);   // [4096,1024]
  u16* QCAT   = alloc(12582912);  // [B,H,S,192]
  u16* KCAT   = alloc(12582912);
  u16* VT     = alloc(8388608);   // [B,H,128,S]
  u16* AOUT   = alloc(8388608);   // [4096,2048]
  float* COS_T = (float*)alloc(131072);
  float* SIN_T = (float*)alloc(131072);

  // Fused prep: f2b(x) + all weight transposes + rope table.
  prep_kernel<<<10912, 256, 0, stream>>>(xf, XB,
                                         wckvf, WCKV_T, wcqf, WCQ_T, wkrf, WKR_T,
                                         wkf, WK_T, wvf, WV_T, wqf, WQ_T,
                                         wqrf, WQR_T, wof, WO_T,
                                         COS_T, SIN_T);

  const float SC = 0.07216878364870323f;  // 1/sqrt(192)
  // G1: x @ [w_ckv | w_cq | w_kr]  -> CC [4096,1088].  288 blocks (9x32).
  gemm_bt_kernel<0><<<288, 256, 0, stream>>>(XB, 2048, WCKV_T, CC,
                                             nullptr, nullptr, nullptr,
                                             4096, 1088, 2048, 9, 1.0f);
  // G23: {c_kv,c_q} @ [wk|wv|wq|wqr] -> KCAT + VT + QCAT(scaled) + QR.
  // 1792 blocks (56x32), K=512.
  gemm_bt_kernel<6><<<1792, 256, 0, stream>>>(CC, 1088, WK_T, KCAT, VT, QCAT, QR,
                                              4096, 7168, 512, 56, SC);

  rope_assemble_kernel<<<8192, 256, 0, stream>>>(QR, CC, COS_T, SIN_T, QCAT, KCAT);

  attn_kernel<<<512, 512, 0, stream>>>(QCAT, KCAT, VT, AOUT);

  // G4: attn_out @ w_o -> d_out (fp32). 512 blocks (16x32).
  gemm_bt_kernel<1><<<512, 256, 0, stream>>>(AOUT, 2048, WO_T, d_out,
                                             nullptr, nullptr, nullptr,
                                             4096, 2048, 2048, 16, 1.0f);
}